// Round 1
// baseline (121.433 us; speedup 1.0000x reference)
//
#include <hip/hip_runtime.h>
#include <math.h>

// Problem constants (B=2, T=4096, n=4, D=2048)
#define DM      8192      // n*D flattened feature dim
#define NK      24        // 4 pre + 4 post + 16 res dot products
#define NACC    25        // + 1 for sum(x^2)
#define NTOK    8192      // B*T tokens
#define NGRP    8         // d-groups across blocks
#define DPG     1024      // d per group
#define TPB     256

// ---------------------------------------------------------------------------
// Kernel 1: Wc[d*24+k] = alpha_k * W_k[d] * rms_w[d]   (d-major, 786 KB)
// ---------------------------------------------------------------------------
__global__ void combine_w(const float* __restrict__ rms_w,
                          const float* __restrict__ w_pre,
                          const float* __restrict__ w_post,
                          const float* __restrict__ w_res,
                          const float* __restrict__ a_pre,
                          const float* __restrict__ a_post,
                          const float* __restrict__ a_res,
                          float* __restrict__ Wc) {
    int idx = blockIdx.x * blockDim.x + threadIdx.x;
    if (idx >= DM * NK) return;
    int d = idx / NK;
    int k = idx - d * NK;
    float w, a;
    if (k < 4)      { w = w_pre [(size_t)k       * DM + d]; a = a_pre[0];  }
    else if (k < 8) { w = w_post[(size_t)(k - 4) * DM + d]; a = a_post[0]; }
    else            { w = w_res [(size_t)(k - 8) * DM + d]; a = a_res[0];  }
    Wc[idx] = a * w * rms_w[d];
}

// ---------------------------------------------------------------------------
// Kernel 2: streaming partial dots. Block = 64 tokens x 1024 d.
//   - stage 64x64 x-slab into LDS (coalesced), transpose: thread owns a token
//   - wave w owns 16-d quarter of each slab -> weight address wave-uniform
//   - 25 accumulators per thread; cross-wave reduce in LDS; write partials
// partial layout: part[(grp*25 + c)*NTOK + token]  (coalesced both ends)
// ---------------------------------------------------------------------------
__global__ __launch_bounds__(TPB) void partial_k(const float* __restrict__ x,
                                                 const float* __restrict__ Wc,
                                                 float* __restrict__ part) {
    // tile region: 64 rows x 68 floats (pad 4 keeps float4 align, kills
    // power-of-2 bank stride) = 4352 floats; reduce region needs 6400.
    __shared__ float smem[6400];

    const int t    = threadIdx.x;
    const int tile = blockIdx.x;           // 0..127 token tiles
    const int grp  = blockIdx.y;           // 0..7  d groups
    const int ltok = t & 63;               // token owned in compute phase
    const int q    = __builtin_amdgcn_readfirstlane(t >> 6);  // wave id, uniform

    float acc[NACC];
#pragma unroll
    for (int c = 0; c < NACC; ++c) acc[c] = 0.0f;

    const int dbase = grp * DPG;
    const float* xrow = x + (size_t)tile * 64 * DM;
    const int dcol = (t & 15) * 4;
    const int rhi  = t >> 4;               // 0..15

    for (int s = 0; s < 16; ++s) {         // 16 slabs of 64 d
        // ---- stage 64 tokens x 64 d (coalesced float4) ----
#pragma unroll
        for (int rr = 0; rr < 4; ++rr) {
            const int row = rr * 16 + rhi;
            const float4 v = *(const float4*)(xrow + (size_t)row * DM +
                                              dbase + s * 64 + dcol);
            *(float4*)(&smem[row * 68 + dcol]) = v;
        }
        __syncthreads();

        // ---- compute: this thread's token, this wave's 16-d quarter ----
        const float* wbase = Wc + (size_t)(dbase + s * 64 + q * 16) * NK;
#pragma unroll
        for (int j = 0; j < 4; ++j) {
            const float4 xv = *(const float4*)(&smem[ltok * 68 + q * 16 + j * 4]);
            const float xs[4] = {xv.x, xv.y, xv.z, xv.w};
#pragma unroll
            for (int e = 0; e < 4; ++e) {
                const float xe = xs[e];
                const float* wp = wbase + (j * 4 + e) * NK;  // wave-uniform
#pragma unroll
                for (int k = 0; k < NK; ++k)
                    acc[k] = fmaf(xe, wp[k], acc[k]);
                acc[24] = fmaf(xe, xe, acc[24]);
            }
        }
        __syncthreads();
    }

    // ---- cross-wave reduce (4 waves hold quarters of each token) ----
#pragma unroll
    for (int c = 0; c < NACC; ++c) smem[t * NACC + c] = acc[c];
    __syncthreads();
    if (t < 64) {
        const int token = tile * 64 + t;
#pragma unroll
        for (int c = 0; c < NACC; ++c) {
            const float v = smem[t * NACC + c] + smem[(t + 64) * NACC + c] +
                            smem[(t + 128) * NACC + c] + smem[(t + 192) * NACC + c];
            part[(size_t)(grp * NACC + c) * NTOK + token] = v;
        }
    }
}

// ---------------------------------------------------------------------------
// Kernel 3: per-token finalize: sum partials, rstd, sigmoids, Sinkhorn(20).
// ---------------------------------------------------------------------------
__global__ void finalize_k(const float* __restrict__ part,
                           const float* __restrict__ b_pre,
                           const float* __restrict__ b_post,
                           const float* __restrict__ b_res,
                           float* __restrict__ out) {
    const int tk = blockIdx.x * blockDim.x + threadIdx.x;
    if (tk >= NTOK) return;

    float v[NACC];
#pragma unroll
    for (int c = 0; c < NACC; ++c) v[c] = 0.0f;
    for (int g = 0; g < NGRP; ++g) {
#pragma unroll
        for (int c = 0; c < NACC; ++c)
            v[c] += part[(size_t)(g * NACC + c) * NTOK + tk];  // coalesced
    }

    const float rstd = rsqrtf(v[24] * (1.0f / (float)DM) + 1e-6f);

    float* out_pre  = out;                 // [NTOK][4]
    float* out_post = out + (size_t)NTOK * 4;
    float* out_res  = out + (size_t)NTOK * 8;

#pragma unroll
    for (int j = 0; j < 4; ++j) {
        const float lp = fmaf(v[j], rstd, b_pre[j]);
        out_pre[tk * 4 + j] = 1.0f / (1.0f + expf(-lp));
        const float lq = fmaf(v[4 + j], rstd, b_post[j]);
        out_post[tk * 4 + j] = 2.0f / (1.0f + expf(-lq));
    }

    // Sinkhorn-Knopp on 4x4, all in registers, statically indexed
    float M[4][4];
#pragma unroll
    for (int i = 0; i < 4; ++i) {
        float l[4];
#pragma unroll
        for (int j = 0; j < 4; ++j)
            l[j] = fmaf(v[8 + i * 4 + j], rstd, b_res[i * 4 + j]);
        const float m = fmaxf(fmaxf(l[0], l[1]), fmaxf(l[2], l[3]));
#pragma unroll
        for (int j = 0; j < 4; ++j)
            M[i][j] = fmaxf(expf(l[j] - m), 1e-6f);
    }
    for (int it = 0; it < 20; ++it) {
#pragma unroll
        for (int i = 0; i < 4; ++i) {
            const float s = (M[i][0] + M[i][1]) + (M[i][2] + M[i][3]);
            const float inv = 1.0f / fmaxf(s, 1e-6f);
#pragma unroll
            for (int j = 0; j < 4; ++j) M[i][j] *= inv;
        }
#pragma unroll
        for (int j = 0; j < 4; ++j) {
            const float s = (M[0][j] + M[1][j]) + (M[2][j] + M[3][j]);
            const float inv = 1.0f / fmaxf(s, 1e-6f);
#pragma unroll
            for (int i = 0; i < 4; ++i) M[i][j] *= inv;
        }
    }
#pragma unroll
    for (int i = 0; i < 4; ++i)
#pragma unroll
        for (int j = 0; j < 4; ++j)
            out_res[(size_t)tk * 16 + i * 4 + j] = M[i][j];
}

// ---------------------------------------------------------------------------
extern "C" void kernel_launch(void* const* d_in, const int* in_sizes, int n_in,
                              void* d_out, int out_size, void* d_ws, size_t ws_size,
                              hipStream_t stream) {
    const float* x      = (const float*)d_in[0];   // (2,4096,4,2048) fp32
    const float* rms_w  = (const float*)d_in[1];   // (8192,)
    const float* w_pre  = (const float*)d_in[2];   // (4,8192)
    const float* w_post = (const float*)d_in[3];   // (4,8192)
    const float* w_res  = (const float*)d_in[4];   // (16,8192)
    const float* b_pre  = (const float*)d_in[5];   // (4,)
    const float* b_post = (const float*)d_in[6];   // (4,)
    const float* b_res  = (const float*)d_in[7];   // (4,4)
    const float* a_pre  = (const float*)d_in[8];   // scalar
    const float* a_post = (const float*)d_in[9];   // scalar
    const float* a_res  = (const float*)d_in[10];  // scalar
    float* out = (float*)d_out;

    // workspace: Wc (8192*24 floats) then partials (8*25*8192 floats) = 7.34 MB
    float* Wc   = (float*)d_ws;
    float* part = (float*)d_ws + (size_t)DM * NK;

    combine_w<<<(DM * NK + TPB - 1) / TPB, TPB, 0, stream>>>(
        rms_w, w_pre, w_post, w_res, a_pre, a_post, a_res, Wc);

    partial_k<<<dim3(NTOK / 64, NGRP), TPB, 0, stream>>>(x, Wc, part);

    finalize_k<<<NTOK / TPB, TPB, 0, stream>>>(part, b_pre, b_post, b_res, out);
}